// Round 14
// baseline (468.659 us; speedup 1.0000x reference)
//
#include <hip/hip_runtime.h>
#include <cfloat>
#include <cmath>

#define NEG_SLOPE 0.2f
#define SOFT_EPS 1e-16f
#define LOG2E 1.4426950408889634f

typedef __bf16 bf16_t;
typedef bf16_t bf16x8 __attribute__((ext_vector_type(8)));
typedef float floatx4 __attribute__((ext_vector_type(4)));
typedef float floatx2 __attribute__((ext_vector_type(2)));

__device__ __forceinline__ float leaky(float x) { return fmaxf(x, NEG_SLOPE * x); }

// fast transcendentals: v_exp_f32 / v_rcp_f32 (~1 ulp) — error invisible at bf16
__device__ __forceinline__ float fast_exp(float x) {
  return __builtin_amdgcn_exp2f(x * LOG2E);
}
__device__ __forceinline__ float fast_tanh(float x) {
  float xc = fminf(fmaxf(x, -15.f), 15.f);
  float t = __builtin_amdgcn_exp2f(xc * (2.f * LOG2E));
  return 1.f - 2.f * __builtin_amdgcn_rcpf(t + 1.f);
}

__device__ __forceinline__ unsigned short f2bf(float f) {
  unsigned u = __float_as_uint(f);
  unsigned r = u + 0x7fffu + ((u >> 16) & 1u);   // round-to-nearest-even
  return (unsigned short)(r >> 16);
}

// order-monotonic encoding of float into unsigned (for hardware atomicMax)
__device__ __forceinline__ unsigned enc_f(float f) {
  unsigned u = __float_as_uint(f);
  return (u & 0x80000000u) ? ~u : (u | 0x80000000u);
}
__device__ __forceinline__ float dec_f(unsigned e) {
  unsigned u = (e & 0x80000000u) ? (e ^ 0x80000000u) : ~e;
  return __uint_as_float(u);
}

// ---------------- CSR build ----------------
// Pass 1: count AND record each edge's rank (atomic return value). 4 edges per
// thread in grid-stride batches: 4 independent atomics in flight overlap the
// ~500-cyc L2-atomic latency 4x (R13 post-mortem: 1-atomic-per-thread = ~45 us/pass).
__global__ __launch_bounds__(256) void count_deg(const int* __restrict__ ei, int E, int N,
                          int* __restrict__ counts, int* __restrict__ rank) {
  int S = gridDim.x * 256;
  int e0 = blockIdx.x * 256 + threadIdx.x;
  int Etot = E + N;
  int d[4], r[4];
#pragma unroll
  for (int j = 0; j < 4; ++j) {
    int e = e0 + j * S;
    if (e < Etot) d[j] = (e < E) ? ei[E + e] : (e - E);
  }
#pragma unroll
  for (int j = 0; j < 4; ++j) {
    int e = e0 + j * S;
    if (e < Etot) r[j] = atomicAdd(&counts[d[j]], 1);
  }
#pragma unroll
  for (int j = 0; j < 4; ++j) {
    int e = e0 + j * S;
    if (e < Etot) rank[e] = r[j];
  }
}

__global__ __launch_bounds__(256) void chunk_sum(const int* __restrict__ counts,
                                                 int* __restrict__ chunkSum, int N) {
  __shared__ int sc[256];
  int b = blockIdx.x, t = threadIdx.x;
  int base = b * 2048 + t * 8;
  int s = 0;
#pragma unroll
  for (int i = 0; i < 8; ++i) { int idx = base + i; if (idx < N) s += counts[idx]; }
  sc[t] = s; __syncthreads();
  for (int o = 128; o > 0; o >>= 1) { if (t < o) sc[t] += sc[t + o]; __syncthreads(); }
  if (t == 0) chunkSum[b] = sc[0];
}

// also initializes the readout accumulators (fused to save a launch)
__global__ void scan_chunks(const int* __restrict__ chunkSum, int* __restrict__ chunkOff,
                            int nb, int* __restrict__ row_start, int N, int Etot,
                            unsigned* __restrict__ gmax, float* __restrict__ gsum,
                            int* __restrict__ cnt) {
  int t = threadIdx.x;
  for (int i = t; i < 64 * 64; i += 64) { gmax[i] = 0x007FFFFFu; gsum[i] = 0.f; }
  cnt[t] = 0;
  if (t == 0) {
    int r = 0;
    for (int b = 0; b < nb; ++b) { chunkOff[b] = r; r += chunkSum[b]; }
    row_start[N] = Etot;
  }
}

__global__ __launch_bounds__(256) void scan_emit(const int* __restrict__ counts,
    const int* __restrict__ chunkOff, int* __restrict__ row_start, int N) {
  __shared__ int sc[256];
  int b = blockIdx.x, t = threadIdx.x;
  int base = b * 2048 + t * 8;
  int v[8]; int s = 0;
#pragma unroll
  for (int i = 0; i < 8; ++i) { int idx = base + i; v[i] = (idx < N) ? counts[idx] : 0; s += v[i]; }
  sc[t] = s; __syncthreads();
  for (int o = 1; o < 256; o <<= 1) {
    int x = (t >= o) ? sc[t - o] : 0;
    __syncthreads();
    sc[t] += x;
    __syncthreads();
  }
  int run = chunkOff[b] + sc[t] - s;
#pragma unroll
  for (int i = 0; i < 8; ++i) {
    int idx = base + i;
    if (idx < N) row_start[idx] = run;
    run += v[i];
  }
}

// atomic-free scatter: pos = row_start[d] + rank[e]; 4 edges/thread so the
// random row_start reads overlap.
__global__ __launch_bounds__(256) void scatter_edges(const int* __restrict__ ei, int E, int N,
                              const int* __restrict__ row_start,
                              const int* __restrict__ rank,
                              int* __restrict__ edge_src) {
  int S = gridDim.x * 256;
  int e0 = blockIdx.x * 256 + threadIdx.x;
  int Etot = E + N;
  int s[4], d[4], rk[4], rs[4];
#pragma unroll
  for (int j = 0; j < 4; ++j) {
    int e = e0 + j * S;
    if (e < Etot) {
      if (e < E) { s[j] = ei[e]; d[j] = ei[E + e]; } else { s[j] = e - E; d[j] = e - E; }
      rk[j] = rank[e];
    }
  }
#pragma unroll
  for (int j = 0; j < 4; ++j) {
    int e = e0 + j * S;
    if (e < Etot) rs[j] = row_start[d[j]];
  }
#pragma unroll
  for (int j = 0; j < 4; ++j) {
    int e = e0 + j * S;
    if (e < Etot) edge_src[rs[j] + rk[j]] = s[j];
  }
}

// ---------------- dtype conversion ----------------
__global__ __launch_bounds__(256) void cvt_bf16(const float* __restrict__ in,
                                                unsigned short* __restrict__ out, int n4) {
  int i = blockIdx.x * 256 + threadIdx.x;
  if (i >= n4) return;
  float4 v = ((const float4*)in)[i];
  ushort4 o;
  o.x = f2bf(v.x); o.y = f2bf(v.y); o.z = f2bf(v.z); o.w = f2bf(v.w);
  ((ushort4*)out)[i] = o;
}

// all three weights in one launch. W[K][256] -> Wt_bf16[256][K]
__global__ __launch_bounds__(256) void cvt_wt3(const float* __restrict__ W0,
    const float* __restrict__ W1, const float* __restrict__ W2,
    unsigned short* __restrict__ T0, unsigned short* __restrict__ T1,
    unsigned short* __restrict__ T2, int K0) {
  const float* W; unsigned short* T; int K;
  if (blockIdx.z == 0)      { W = W0; T = T0; K = K0; }
  else if (blockIdx.z == 1) { W = W1; T = T1; K = 256; }
  else                      { W = W2; T = T2; K = 256; }
  int tx = threadIdx.x & 15, ty = threadIdx.x >> 4;
  int k = blockIdx.x * 16 + tx;
  int n = blockIdx.y * 16 + ty;
  if (k < K) T[(size_t)n * K + k] = f2bf(W[(size_t)k * 256 + n]);
}

// ---- MFMA GEMM (global_load_lds staging, fragment-major LDS) + fused attention
// dots + 2-phase LDS-transposed coalesced fp8 C store ---- (R10 proven version)
#define BM 128
#define BN 128
#define BK 64

__global__ __launch_bounds__(256) void gemm_core(const unsigned short* __restrict__ A,
    const unsigned short* __restrict__ Bt, unsigned char* __restrict__ Cout8,
    float* __restrict__ a_src, float* __restrict__ a_dst,
    const float* __restrict__ attS, const float* __restrict__ attD, int N, int K) {
  // 34304 B: staging uses first 32768 (A [0,8192) ushorts, B [8192,16384));
  // epilogue reuses as 64x132 float transpose buffer (needs 33792 B)
  __shared__ __align__(16) unsigned char ldsraw[34304];
  unsigned short* ldsbuf = (unsigned short*)ldsraw;
  int t = threadIdx.x;
  int wave = t >> 6, lane = t & 63;
  int wm = wave & 1, wn = wave >> 1;
  int row0 = blockIdx.y * BM;
  int col0 = blockIdx.x * BN;
  floatx4 acc[4][4] = {};

  int rbase = (lane & 15);
  int kq8 = (lane >> 4) * 8;

  for (int k0 = 0; k0 < K; k0 += BK) {
#pragma unroll
    for (int rr = 0; rr < 4; ++rr) {
      int R = wave * 4 + rr;                       // 0..15
      int grow = row0 + (R >> 1) * 16 + rbase;     // over-read lands in ws, discarded
      int gk = k0 + (R & 1) * 32 + kq8;
      const unsigned short* ga = A + (size_t)grow * K + gk;
      __builtin_amdgcn_global_load_lds(
          (const __attribute__((address_space(1))) void*)ga,
          (__attribute__((address_space(3))) void*)(ldsbuf + R * 512), 16, 0, 0);
      int gcol = col0 + (R >> 1) * 16 + rbase;
      const unsigned short* gb = Bt + (size_t)gcol * K + gk;
      __builtin_amdgcn_global_load_lds(
          (const __attribute__((address_space(1))) void*)gb,
          (__attribute__((address_space(3))) void*)(ldsbuf + 8192 + R * 512), 16, 0, 0);
    }
    __syncthreads();
#pragma unroll
    for (int ks = 0; ks < 2; ++ks) {
      bf16x8 af[4], bfr[4];
#pragma unroll
      for (int i = 0; i < 4; ++i)
        af[i] = *(const bf16x8*)(ldsbuf + ((wm * 4 + i) * 2 + ks) * 512 + lane * 8);
#pragma unroll
      for (int j = 0; j < 4; ++j)
        bfr[j] = *(const bf16x8*)(ldsbuf + 8192 + ((wn * 4 + j) * 2 + ks) * 512 + lane * 8);
#pragma unroll
      for (int i = 0; i < 4; ++i)
#pragma unroll
        for (int j = 0; j < 4; ++j)
          acc[i][j] = __builtin_amdgcn_mfma_f32_16x16x32_bf16(af[i], bfr[j], acc[i][j], 0, 0, 0);
    }
    __syncthreads();
  }

  // fused attention dots (register-only; before LDS reuse)
  int head = blockIdx.x * 2 + wn;
  int cin = lane & 15;
  float aS[4], aD[4];
#pragma unroll
  for (int j = 0; j < 4; ++j) {
    aS[j] = attS[head * 64 + j * 16 + cin];
    aD[j] = attD[head * 64 + j * 16 + cin];
  }
#pragma unroll
  for (int i = 0; i < 4; ++i) {
    floatx4 ps = {0.f, 0.f, 0.f, 0.f}, pd = {0.f, 0.f, 0.f, 0.f};
#pragma unroll
    for (int j = 0; j < 4; ++j) {
      ps += acc[i][j] * aS[j];
      pd += acc[i][j] * aD[j];
    }
#pragma unroll
    for (int m = 1; m < 16; m <<= 1) {
#pragma unroll
      for (int k = 0; k < 4; ++k) {
        ps[k] += __shfl_xor(ps[k], m, 64);
        pd[k] += __shfl_xor(pd[k], m, 64);
      }
    }
    if ((lane & 15) == 0) {
      int rb = row0 + wm * 64 + i * 16 + (lane >> 4) * 4;
#pragma unroll
      for (int reg = 0; reg < 4; ++reg) {
        int r = rb + reg;
        if (r < N) {
          a_src[r * 4 + head] = ps[reg];
          a_dst[r * 4 + head] = pd[reg];
        }
      }
    }
  }

  // C store: 2 phases of 64 rows through LDS (132-float padded rows).
  // Per phase: 64 rows x 8 chunks of 16 cols = 512 uint4 stores (2 per thread).
  float* ldsf = (float*)ldsraw;
#pragma unroll
  for (int p = 0; p < 2; ++p) {
    __syncthreads();
    if (wm == p) {
#pragma unroll
      for (int i = 0; i < 4; ++i) {
        int rloc = i * 16 + (lane >> 4) * 4;
#pragma unroll
        for (int j = 0; j < 4; ++j) {
          int col = wn * 64 + j * 16 + (lane & 15);
#pragma unroll
          for (int reg = 0; reg < 4; ++reg)
            ldsf[(rloc + reg) * 132 + col] = acc[i][j][reg];
        }
      }
    }
    __syncthreads();
    int browbase = row0 + p * 64;
#pragma unroll
    for (int q = 0; q < 2; ++q) {
      int idx = t + 256 * q;          // 0..511
      int prow = idx >> 3;            // 0..63
      int cb = (idx & 7) * 16;        // 0..112 (float/col base within 128-col row)
      int grow = browbase + prow;
      if (grow < N) {
        const float* fp = &ldsf[prow * 132 + cb];
        unsigned ov[4];
#pragma unroll
        for (int q4 = 0; q4 < 4; ++q4) {
          unsigned v = 0;
          v = __builtin_amdgcn_cvt_pk_fp8_f32(fp[q4 * 4 + 0], fp[q4 * 4 + 1], v, false);
          v = __builtin_amdgcn_cvt_pk_fp8_f32(fp[q4 * 4 + 2], fp[q4 * 4 + 3], v, true);
          ov[q4] = v;
        }
        *(uint4*)(Cout8 + (size_t)grow * 256 + col0 + cb) =
            make_uint4(ov[0], ov[1], ov[2], ov[3]);
      }
    }
  }
}

// ---------------- fused per-dst: exp + softmax-denominator + aggregate + bias + tanh ----
__global__ __launch_bounds__(256) void attn_agg(const unsigned char* __restrict__ g8,
    const float* __restrict__ a_src, const float* __restrict__ a_dst,
    const int* __restrict__ row_start, const int* __restrict__ edge_src,
    const float* __restrict__ bias,
    unsigned short* __restrict__ hout_bf, float* __restrict__ nodemean, int N) {
  __shared__ float els[4][64 * 4];
  int lane = threadIdx.x & 63;
  int w = threadIdx.x >> 6;
  int n = blockIdx.x * 4 + w;
  if (n >= N) return;
  int beg = row_start[n], end = row_start[n + 1];
  float* ew = els[w];

  float4 adn = *(const float4*)(a_dst + (size_t)n * 4);

  // pass 1: per-edge exp for 4 heads + denominators
  float4 dv = make_float4(0.f, 0.f, 0.f, 0.f);
  for (int i = beg + lane; i < end; i += 64) {
    int s = edge_src[i];
    float4 as = *(const float4*)(a_src + (size_t)s * 4);
    float4 ev;
    ev.x = fast_exp(fminf(leaky(as.x + adn.x), 60.f));
    ev.y = fast_exp(fminf(leaky(as.y + adn.y), 60.f));
    ev.z = fast_exp(fminf(leaky(as.z + adn.z), 60.f));
    ev.w = fast_exp(fminf(leaky(as.w + adn.w), 60.f));
    int idx = i - beg;
    if (idx < 64) *(float4*)(&ew[idx * 4]) = ev;
    dv.x += ev.x; dv.y += ev.y; dv.z += ev.z; dv.w += ev.w;
  }
  for (int m = 1; m < 64; m <<= 1) {
    dv.x += __shfl_xor(dv.x, m, 64);
    dv.y += __shfl_xor(dv.y, m, 64);
    dv.z += __shfl_xor(dv.z, m, 64);
    dv.w += __shfl_xor(dv.w, m, 64);
  }

  int half = lane >> 5;
  int l = lane & 31;
  int h = l >> 3;          // head for this lane's 8 channels
  int c0 = l * 8;          // channel base (0..248)
  float den = (h == 0) ? dv.x : (h == 1) ? dv.y : (h == 2) ? dv.z : dv.w;
  float adh = (h == 0) ? adn.x : (h == 1) ? adn.y : (h == 2) ? adn.z : adn.w;
  float invh = __builtin_amdgcn_rcpf(den + SOFT_EPS);

  auto EG = [&](int i) -> float {
    int idx = i - beg;
    if (idx < 64) return ew[idx * 4 + h];
    int s = edge_src[i];
    return fast_exp(fminf(leaky(a_src[(size_t)s * 4 + h] + adh), 60.f));
  };

  // pass 2: gather (fp8 rows), unnormalized, packed f32 accumulation
  floatx2 p0 = {0.f, 0.f}, p1 = {0.f, 0.f}, p2 = {0.f, 0.f}, p3 = {0.f, 0.f};
  int i = beg + half;
  for (; i + 6 < end; i += 8) {
    int s0 = edge_src[i];
    int s1 = edge_src[i + 2];
    int s2 = edge_src[i + 4];
    int s3 = edge_src[i + 6];
    float e0 = EG(i);
    float e1 = EG(i + 2);
    float e2 = EG(i + 4);
    float e3 = EG(i + 6);
    uint2 g0 = *(const uint2*)(g8 + (size_t)s0 * 256 + c0);
    uint2 g1 = *(const uint2*)(g8 + (size_t)s1 * 256 + c0);
    uint2 g2 = *(const uint2*)(g8 + (size_t)s2 * 256 + c0);
    uint2 g3 = *(const uint2*)(g8 + (size_t)s3 * 256 + c0);
    p0 += e0 * (floatx2)__builtin_amdgcn_cvt_pk_f32_fp8(g0.x, false)
        + e1 * (floatx2)__builtin_amdgcn_cvt_pk_f32_fp8(g1.x, false)
        + e2 * (floatx2)__builtin_amdgcn_cvt_pk_f32_fp8(g2.x, false)
        + e3 * (floatx2)__builtin_amdgcn_cvt_pk_f32_fp8(g3.x, false);
    p1 += e0 * (floatx2)__builtin_amdgcn_cvt_pk_f32_fp8(g0.x, true)
        + e1 * (floatx2)__builtin_amdgcn_cvt_pk_f32_fp8(g1.x, true)
        + e2 * (floatx2)__builtin_amdgcn_cvt_pk_f32_fp8(g2.x, true)
        + e3 * (floatx2)__builtin_amdgcn_cvt_pk_f32_fp8(g3.x, true);
    p2 += e0 * (floatx2)__builtin_amdgcn_cvt_pk_f32_fp8(g0.y, false)
        + e1 * (floatx2)__builtin_amdgcn_cvt_pk_f32_fp8(g1.y, false)
        + e2 * (floatx2)__builtin_amdgcn_cvt_pk_f32_fp8(g2.y, false)
        + e3 * (floatx2)__builtin_amdgcn_cvt_pk_f32_fp8(g3.y, false);
    p3 += e0 * (floatx2)__builtin_amdgcn_cvt_pk_f32_fp8(g0.y, true)
        + e1 * (floatx2)__builtin_amdgcn_cvt_pk_f32_fp8(g1.y, true)
        + e2 * (floatx2)__builtin_amdgcn_cvt_pk_f32_fp8(g2.y, true)
        + e3 * (floatx2)__builtin_amdgcn_cvt_pk_f32_fp8(g3.y, true);
  }
  for (; i < end; i += 2) {
    int s = edge_src[i];
    float e0 = EG(i);
    uint2 gv = *(const uint2*)(g8 + (size_t)s * 256 + c0);
    p0 += e0 * (floatx2)__builtin_amdgcn_cvt_pk_f32_fp8(gv.x, false);
    p1 += e0 * (floatx2)__builtin_amdgcn_cvt_pk_f32_fp8(gv.x, true);
    p2 += e0 * (floatx2)__builtin_amdgcn_cvt_pk_f32_fp8(gv.y, false);
    p3 += e0 * (floatx2)__builtin_amdgcn_cvt_pk_f32_fp8(gv.y, true);
  }
  float a0 = p0[0], a1 = p0[1], a2 = p1[0], a3 = p1[1];
  float a4 = p2[0], a5 = p2[1], a6 = p3[0], a7 = p3[1];
  a0 += __shfl_xor(a0, 32, 64); a1 += __shfl_xor(a1, 32, 64);
  a2 += __shfl_xor(a2, 32, 64); a3 += __shfl_xor(a3, 32, 64);
  a4 += __shfl_xor(a4, 32, 64); a5 += __shfl_xor(a5, 32, 64);
  a6 += __shfl_xor(a6, 32, 64); a7 += __shfl_xor(a7, 32, 64);
  a0 *= invh; a1 *= invh; a2 *= invh; a3 *= invh;
  a4 *= invh; a5 *= invh; a6 *= invh; a7 *= invh;

  float4 b01 = *(const float4*)(bias + c0);
  float4 b23 = *(const float4*)(bias + c0 + 4);
  float o0 = fast_tanh(a0 + b01.x), o1 = fast_tanh(a1 + b01.y);
  float o2 = fast_tanh(a2 + b01.z), o3 = fast_tanh(a3 + b01.w);
  float o4 = fast_tanh(a4 + b23.x), o5 = fast_tanh(a5 + b23.y);
  float o6 = fast_tanh(a6 + b23.z), o7 = fast_tanh(a7 + b23.w);

  if (hout_bf) {
    if (half == 0) {
      unsigned q0 = (unsigned)f2bf(o0) | ((unsigned)f2bf(o1) << 16);
      unsigned q1 = (unsigned)f2bf(o2) | ((unsigned)f2bf(o3) << 16);
      unsigned q2 = (unsigned)f2bf(o4) | ((unsigned)f2bf(o5) << 16);
      unsigned q3 = (unsigned)f2bf(o6) | ((unsigned)f2bf(o7) << 16);
      *(uint4*)(hout_bf + (size_t)n * 256 + c0) = make_uint4(q0, q1, q2, q3);
    }
  } else {
    o0 += __shfl_xor(o0, 8, 64);  o1 += __shfl_xor(o1, 8, 64);
    o2 += __shfl_xor(o2, 8, 64);  o3 += __shfl_xor(o3, 8, 64);
    o4 += __shfl_xor(o4, 8, 64);  o5 += __shfl_xor(o5, 8, 64);
    o6 += __shfl_xor(o6, 8, 64);  o7 += __shfl_xor(o7, 8, 64);
    o0 += __shfl_xor(o0, 16, 64); o1 += __shfl_xor(o1, 16, 64);
    o2 += __shfl_xor(o2, 16, 64); o3 += __shfl_xor(o3, 16, 64);
    o4 += __shfl_xor(o4, 16, 64); o5 += __shfl_xor(o5, 16, 64);
    o6 += __shfl_xor(o6, 16, 64); o7 += __shfl_xor(o7, 16, 64);
    if (half == 0 && l < 8) {
      float* np = nodemean + (size_t)n * 64 + l * 8;
      *(float4*)(np)     = make_float4(0.25f * o0, 0.25f * o1, 0.25f * o2, 0.25f * o3);
      *(float4*)(np + 4) = make_float4(0.25f * o4, 0.25f * o5, 0.25f * o6, 0.25f * o7);
    }
  }
}

// ---------------- readout ----------------
#define RNPB 256
__global__ __launch_bounds__(256) void readout_nodes(const float* __restrict__ nm,
    const int* __restrict__ batch, unsigned* __restrict__ gmax,
    float* __restrict__ gsum, int* __restrict__ cnt, int N) {
  int t = threadIdx.x;
  int c = t & 63;
  int q = t >> 6;
  int n0 = blockIdx.x * RNPB + q * (RNPB / 4);
  if (n0 >= N) return;
  int n1 = min(n0 + RNPB / 4, N);
  float vmax = -FLT_MAX, vsum = 0.f;
  int curb = batch[n0];
  int cl = 0;
  for (int n = n0; n < n1; ++n) {
    int b = batch[n];
    if (b != curb) {
      atomicMax(&gmax[curb * 64 + c], enc_f(vmax));
      atomicAdd(&gsum[curb * 64 + c], vsum);
      if (c == 0) atomicAdd(&cnt[curb], cl);
      vmax = -FLT_MAX; vsum = 0.f; cl = 0; curb = b;
    }
    float v = nm[(size_t)n * 64 + c];
    vmax = fmaxf(vmax, v); vsum += v; ++cl;
  }
  atomicMax(&gmax[curb * 64 + c], enc_f(vmax));
  atomicAdd(&gsum[curb * 64 + c], vsum);
  if (c == 0) atomicAdd(&cnt[curb], cl);
}

__global__ __launch_bounds__(256) void finalize(const unsigned* __restrict__ gmax,
    const float* __restrict__ gsum, const int* __restrict__ cnt,
    const float* __restrict__ Wout, const float* __restrict__ bout,
    float* __restrict__ out) {
  __shared__ float hid[64 * 192];
  int t = threadIdx.x;
  for (int i = t; i < 64 * 192; i += 256) {
    int b = i / 192, j = i % 192;
    float v;
    if (j < 64) v = dec_f(gmax[b * 64 + j]);
    else if (j < 128) v = gsum[b * 64 + j - 64] / fmaxf((float)cnt[b], 1.f);
    else v = gsum[b * 64 + j - 128];
    hid[i] = v;
    out[1024 + i] = v;
  }
  __syncthreads();
  for (int i = t; i < 64 * 16; i += 256) {
    int b = i >> 4, o = i & 15;
    float s = bout[o];
    for (int k = 0; k < 192; ++k) s += hid[b * 192 + k] * Wout[k * 16 + o];
    out[i] = s;
  }
}

extern "C" void kernel_launch(void* const* d_in, const int* in_sizes, int n_in,
                              void* d_out, int out_size, void* d_ws, size_t ws_size,
                              hipStream_t stream) {
  const float* x     = (const float*)d_in[0];
  const int*   ei    = (const int*)d_in[1];
  const int*   batch = (const int*)d_in[2];
  const float* W[3]  = {(const float*)d_in[3], (const float*)d_in[7], (const float*)d_in[11]};
  const float* as_[3] = {(const float*)d_in[4], (const float*)d_in[8], (const float*)d_in[12]};
  const float* ad_[3] = {(const float*)d_in[5], (const float*)d_in[9], (const float*)d_in[13]};
  const float* bb[3] = {(const float*)d_in[6], (const float*)d_in[10], (const float*)d_in[14]};
  const float* Wout  = (const float*)d_in[15];
  const float* bout  = (const float*)d_in[16];
  float* out = (float*)d_out;

  int N    = in_sizes[2];
  int Fin  = in_sizes[0] / N;
  int E    = in_sizes[1] / 2;
  int Etot = E + N;

  char* ws = (char*)d_ws;
  size_t off = 0;
  auto alloc = [&](size_t bytes) -> void* {
    void* p = ws + off;
    off += bytes;
    off = (off + 255) & ~(size_t)255;
    return p;
  };
  unsigned char* gbuf  = (unsigned char*)alloc((size_t)N * 256);       // gemm out (fp8)
  unsigned short* h0bf = (unsigned short*)alloc((size_t)N * Fin * 2);  // x (bf16)
  unsigned short* h1bf = (unsigned short*)alloc((size_t)N * 256 * 2);  // layer out (bf16)
  float* nodemean  = (float*)alloc((size_t)N * 64 * 4);                // layer-2 head-mean
  unsigned short* Wt[3];
  Wt[0] = (unsigned short*)alloc((size_t)256 * Fin * 2);
  Wt[1] = (unsigned short*)alloc((size_t)256 * 256 * 2);
  Wt[2] = (unsigned short*)alloc((size_t)256 * 256 * 2);
  float* a_src    = (float*)alloc((size_t)N * 4 * 4);
  float* a_dst    = (float*)alloc((size_t)N * 4 * 4);
  int* counts     = (int*)alloc((size_t)N * 4);
  int* row_start  = (int*)alloc((size_t)(N + 1) * 4);
  int* rank       = (int*)alloc((size_t)Etot * 4);
  int* edge_src   = (int*)alloc((size_t)Etot * 4);
  int* chunkSum   = (int*)alloc(64 * 4);
  int* chunkOff   = (int*)alloc(64 * 4);
  unsigned* gmax  = (unsigned*)alloc(64 * 64 * 4);
  float* gsum     = (float*)alloc(64 * 64 * 4);
  int* cnt        = (int*)alloc(64 * 4);

  // ---- CSR build: 1 ILP-batched atomic pass, scan, atomic-free scatter ----
  hipMemsetAsync(counts, 0, (size_t)N * 4, stream);
  int nb = (N + 2047) / 2048;
  int egrid = (Etot + 1023) / 1024;   // 4 edges per thread
  count_deg<<<egrid, 256, 0, stream>>>(ei, E, N, counts, rank);
  chunk_sum<<<nb, 256, 0, stream>>>(counts, chunkSum, N);
  scan_chunks<<<1, 64, 0, stream>>>(chunkSum, chunkOff, nb, row_start, N, Etot,
                                    gmax, gsum, cnt);
  scan_emit<<<nb, 256, 0, stream>>>(counts, chunkOff, row_start, N);
  scatter_edges<<<egrid, 256, 0, stream>>>(ei, E, N, row_start, rank, edge_src);

  // ---- weight transpose-convert (one launch), x convert ----
  cvt_wt3<<<dim3(16, 16, 3), 256, 0, stream>>>(W[0], W[1], W[2], Wt[0], Wt[1], Wt[2], Fin);
  cvt_bf16<<<((N * Fin / 4) + 255) / 256, 256, 0, stream>>>(x, h0bf, N * Fin / 4);

  // ---- 3 GAT layers ----
  const unsigned short* Ain = h0bf;
  int K = Fin;
  for (int l = 0; l < 3; ++l) {
    dim3 gg(2, (N + BM - 1) / BM);
    gemm_core<<<gg, 256, 0, stream>>>(Ain, Wt[l], gbuf, a_src, a_dst,
                                      as_[l], ad_[l], N, K);
    attn_agg<<<(N + 3) / 4, 256, 0, stream>>>(gbuf, a_src, a_dst, row_start, edge_src,
                                              bb[l],
                                              (l < 2) ? h1bf : (unsigned short*)nullptr,
                                              (l == 2) ? nodemean : (float*)nullptr, N);
    Ain = h1bf;
    K = 256;
  }

  // ---- readout ----
  readout_nodes<<<(N + RNPB - 1) / RNPB, 256, 0, stream>>>(nodemean, batch, gmax, gsum, cnt, N);
  finalize<<<1, 256, 0, stream>>>(gmax, gsum, cnt, Wout, bout, out);
}

// Round 15
// 431.701 us; speedup vs baseline: 1.0856x; 1.0856x over previous
//
#include <hip/hip_runtime.h>
#include <cfloat>
#include <cmath>

#define NEG_SLOPE 0.2f
#define SOFT_EPS 1e-16f
#define LOG2E 1.4426950408889634f

typedef __bf16 bf16_t;
typedef bf16_t bf16x8 __attribute__((ext_vector_type(8)));
typedef float floatx4 __attribute__((ext_vector_type(4)));
typedef float floatx2 __attribute__((ext_vector_type(2)));

__device__ __forceinline__ float leaky(float x) { return fmaxf(x, NEG_SLOPE * x); }

// fast transcendentals: v_exp_f32 / v_rcp_f32 (~1 ulp) — error invisible at bf16
__device__ __forceinline__ float fast_exp(float x) {
  return __builtin_amdgcn_exp2f(x * LOG2E);
}
__device__ __forceinline__ float fast_tanh(float x) {
  float xc = fminf(fmaxf(x, -15.f), 15.f);
  float t = __builtin_amdgcn_exp2f(xc * (2.f * LOG2E));
  return 1.f - 2.f * __builtin_amdgcn_rcpf(t + 1.f);
}

__device__ __forceinline__ unsigned short f2bf(float f) {
  unsigned u = __float_as_uint(f);
  unsigned r = u + 0x7fffu + ((u >> 16) & 1u);   // round-to-nearest-even
  return (unsigned short)(r >> 16);
}

// order-monotonic encoding of float into unsigned (for hardware atomicMax)
__device__ __forceinline__ unsigned enc_f(float f) {
  unsigned u = __float_as_uint(f);
  return (u & 0x80000000u) ? ~u : (u | 0x80000000u);
}
__device__ __forceinline__ float dec_f(unsigned e) {
  unsigned u = (e & 0x80000000u) ? (e ^ 0x80000000u) : ~e;
  return __uint_as_float(u);
}

// ---------------- CSR build ----------------
// Pass 1: count AND record each edge's rank (atomic return value).
// (R14 post-mortem: random-address atomics are L2-throughput-bound, ~18k/us
// device-wide; ILP batching is neutral. One atomic per edge is the floor.)
__global__ __launch_bounds__(256) void count_deg(const int* __restrict__ ei, int E, int N,
                          int* __restrict__ counts, int* __restrict__ rank) {
  int S = gridDim.x * 256;
  int e0 = blockIdx.x * 256 + threadIdx.x;
  int Etot = E + N;
  int d[4], r[4];
#pragma unroll
  for (int j = 0; j < 4; ++j) {
    int e = e0 + j * S;
    if (e < Etot) d[j] = (e < E) ? ei[E + e] : (e - E);
  }
#pragma unroll
  for (int j = 0; j < 4; ++j) {
    int e = e0 + j * S;
    if (e < Etot) r[j] = atomicAdd(&counts[d[j]], 1);
  }
#pragma unroll
  for (int j = 0; j < 4; ++j) {
    int e = e0 + j * S;
    if (e < Etot) rank[e] = r[j];
  }
}

__global__ __launch_bounds__(256) void chunk_sum(const int* __restrict__ counts,
                                                 int* __restrict__ chunkSum, int N) {
  __shared__ int sc[256];
  int b = blockIdx.x, t = threadIdx.x;
  int base = b * 2048 + t * 8;
  int s = 0;
#pragma unroll
  for (int i = 0; i < 8; ++i) { int idx = base + i; if (idx < N) s += counts[idx]; }
  sc[t] = s; __syncthreads();
  for (int o = 128; o > 0; o >>= 1) { if (t < o) sc[t] += sc[t + o]; __syncthreads(); }
  if (t == 0) chunkSum[b] = sc[0];
}

// also initializes the readout accumulators (fused to save a launch)
__global__ void scan_chunks(const int* __restrict__ chunkSum, int* __restrict__ chunkOff,
                            int nb, int* __restrict__ row_start, int N, int Etot,
                            unsigned* __restrict__ gmax, float* __restrict__ gsum,
                            int* __restrict__ cnt) {
  int t = threadIdx.x;
  for (int i = t; i < 64 * 64; i += 64) { gmax[i] = 0x007FFFFFu; gsum[i] = 0.f; }
  cnt[t] = 0;
  if (t == 0) {
    int r = 0;
    for (int b = 0; b < nb; ++b) { chunkOff[b] = r; r += chunkSum[b]; }
    row_start[N] = Etot;
  }
}

__global__ __launch_bounds__(256) void scan_emit(const int* __restrict__ counts,
    const int* __restrict__ chunkOff, int* __restrict__ row_start, int N) {
  __shared__ int sc[256];
  int b = blockIdx.x, t = threadIdx.x;
  int base = b * 2048 + t * 8;
  int v[8]; int s = 0;
#pragma unroll
  for (int i = 0; i < 8; ++i) { int idx = base + i; v[i] = (idx < N) ? counts[idx] : 0; s += v[i]; }
  sc[t] = s; __syncthreads();
  for (int o = 1; o < 256; o <<= 1) {
    int x = (t >= o) ? sc[t - o] : 0;
    __syncthreads();
    sc[t] += x;
    __syncthreads();
  }
  int run = chunkOff[b] + sc[t] - s;
#pragma unroll
  for (int i = 0; i < 8; ++i) {
    int idx = base + i;
    if (idx < N) row_start[idx] = run;
    run += v[i];
  }
}

// atomic-free scatter: pos = row_start[d] + rank[e]
__global__ __launch_bounds__(256) void scatter_edges(const int* __restrict__ ei, int E, int N,
                              const int* __restrict__ row_start,
                              const int* __restrict__ rank,
                              int* __restrict__ edge_src) {
  int S = gridDim.x * 256;
  int e0 = blockIdx.x * 256 + threadIdx.x;
  int Etot = E + N;
  int s[4], d[4], rk[4], rs[4];
#pragma unroll
  for (int j = 0; j < 4; ++j) {
    int e = e0 + j * S;
    if (e < Etot) {
      if (e < E) { s[j] = ei[e]; d[j] = ei[E + e]; } else { s[j] = e - E; d[j] = e - E; }
      rk[j] = rank[e];
    }
  }
#pragma unroll
  for (int j = 0; j < 4; ++j) {
    int e = e0 + j * S;
    if (e < Etot) rs[j] = row_start[d[j]];
  }
#pragma unroll
  for (int j = 0; j < 4; ++j) {
    int e = e0 + j * S;
    if (e < Etot) edge_src[rs[j] + rk[j]] = s[j];
  }
}

// ---------------- dtype conversion ----------------
__global__ __launch_bounds__(256) void cvt_bf16(const float* __restrict__ in,
                                                unsigned short* __restrict__ out, int n4) {
  int i = blockIdx.x * 256 + threadIdx.x;
  if (i >= n4) return;
  float4 v = ((const float4*)in)[i];
  ushort4 o;
  o.x = f2bf(v.x); o.y = f2bf(v.y); o.z = f2bf(v.z); o.w = f2bf(v.w);
  ((ushort4*)out)[i] = o;
}

// all three weights in one launch. W[K][256] -> Wt_bf16[256][K]
__global__ __launch_bounds__(256) void cvt_wt3(const float* __restrict__ W0,
    const float* __restrict__ W1, const float* __restrict__ W2,
    unsigned short* __restrict__ T0, unsigned short* __restrict__ T1,
    unsigned short* __restrict__ T2, int K0) {
  const float* W; unsigned short* T; int K;
  if (blockIdx.z == 0)      { W = W0; T = T0; K = K0; }
  else if (blockIdx.z == 1) { W = W1; T = T1; K = 256; }
  else                      { W = W2; T = T2; K = 256; }
  int tx = threadIdx.x & 15, ty = threadIdx.x >> 4;
  int k = blockIdx.x * 16 + tx;
  int n = blockIdx.y * 16 + ty;
  if (k < K) T[(size_t)n * K + k] = f2bf(W[(size_t)k * 256 + n]);
}

// ---- MFMA GEMM (global_load_lds staging, fragment-major LDS) + fused attention
// dots + 2-phase LDS-transposed coalesced fp8 C store ---- (R10 proven version)
#define BM 128
#define BN 128
#define BK 64

__global__ __launch_bounds__(256) void gemm_core(const unsigned short* __restrict__ A,
    const unsigned short* __restrict__ Bt, unsigned char* __restrict__ Cout8,
    float* __restrict__ a_src, float* __restrict__ a_dst,
    const float* __restrict__ attS, const float* __restrict__ attD, int N, int K) {
  // 34304 B: staging uses first 32768 (A [0,8192) ushorts, B [8192,16384));
  // epilogue reuses as 64x132 float transpose buffer (needs 33792 B)
  __shared__ __align__(16) unsigned char ldsraw[34304];
  unsigned short* ldsbuf = (unsigned short*)ldsraw;
  int t = threadIdx.x;
  int wave = t >> 6, lane = t & 63;
  int wm = wave & 1, wn = wave >> 1;
  int row0 = blockIdx.y * BM;
  int col0 = blockIdx.x * BN;
  floatx4 acc[4][4] = {};

  int rbase = (lane & 15);
  int kq8 = (lane >> 4) * 8;

  for (int k0 = 0; k0 < K; k0 += BK) {
#pragma unroll
    for (int rr = 0; rr < 4; ++rr) {
      int R = wave * 4 + rr;                       // 0..15
      int grow = row0 + (R >> 1) * 16 + rbase;     // over-read lands in ws, discarded
      int gk = k0 + (R & 1) * 32 + kq8;
      const unsigned short* ga = A + (size_t)grow * K + gk;
      __builtin_amdgcn_global_load_lds(
          (const __attribute__((address_space(1))) void*)ga,
          (__attribute__((address_space(3))) void*)(ldsbuf + R * 512), 16, 0, 0);
      int gcol = col0 + (R >> 1) * 16 + rbase;
      const unsigned short* gb = Bt + (size_t)gcol * K + gk;
      __builtin_amdgcn_global_load_lds(
          (const __attribute__((address_space(1))) void*)gb,
          (__attribute__((address_space(3))) void*)(ldsbuf + 8192 + R * 512), 16, 0, 0);
    }
    __syncthreads();
#pragma unroll
    for (int ks = 0; ks < 2; ++ks) {
      bf16x8 af[4], bfr[4];
#pragma unroll
      for (int i = 0; i < 4; ++i)
        af[i] = *(const bf16x8*)(ldsbuf + ((wm * 4 + i) * 2 + ks) * 512 + lane * 8);
#pragma unroll
      for (int j = 0; j < 4; ++j)
        bfr[j] = *(const bf16x8*)(ldsbuf + 8192 + ((wn * 4 + j) * 2 + ks) * 512 + lane * 8);
#pragma unroll
      for (int i = 0; i < 4; ++i)
#pragma unroll
        for (int j = 0; j < 4; ++j)
          acc[i][j] = __builtin_amdgcn_mfma_f32_16x16x32_bf16(af[i], bfr[j], acc[i][j], 0, 0, 0);
    }
    __syncthreads();
  }

  // fused attention dots (register-only; before LDS reuse)
  int head = blockIdx.x * 2 + wn;
  int cin = lane & 15;
  float aS[4], aD[4];
#pragma unroll
  for (int j = 0; j < 4; ++j) {
    aS[j] = attS[head * 64 + j * 16 + cin];
    aD[j] = attD[head * 64 + j * 16 + cin];
  }
#pragma unroll
  for (int i = 0; i < 4; ++i) {
    floatx4 ps = {0.f, 0.f, 0.f, 0.f}, pd = {0.f, 0.f, 0.f, 0.f};
#pragma unroll
    for (int j = 0; j < 4; ++j) {
      ps += acc[i][j] * aS[j];
      pd += acc[i][j] * aD[j];
    }
#pragma unroll
    for (int m = 1; m < 16; m <<= 1) {
#pragma unroll
      for (int k = 0; k < 4; ++k) {
        ps[k] += __shfl_xor(ps[k], m, 64);
        pd[k] += __shfl_xor(pd[k], m, 64);
      }
    }
    if ((lane & 15) == 0) {
      int rb = row0 + wm * 64 + i * 16 + (lane >> 4) * 4;
#pragma unroll
      for (int reg = 0; reg < 4; ++reg) {
        int r = rb + reg;
        if (r < N) {
          a_src[r * 4 + head] = ps[reg];
          a_dst[r * 4 + head] = pd[reg];
        }
      }
    }
  }

  // C store: 2 phases of 64 rows through LDS (132-float padded rows).
  // Per phase: 64 rows x 8 chunks of 16 cols = 512 uint4 stores (2 per thread).
  float* ldsf = (float*)ldsraw;
#pragma unroll
  for (int p = 0; p < 2; ++p) {
    __syncthreads();
    if (wm == p) {
#pragma unroll
      for (int i = 0; i < 4; ++i) {
        int rloc = i * 16 + (lane >> 4) * 4;
#pragma unroll
        for (int j = 0; j < 4; ++j) {
          int col = wn * 64 + j * 16 + (lane & 15);
#pragma unroll
          for (int reg = 0; reg < 4; ++reg)
            ldsf[(rloc + reg) * 132 + col] = acc[i][j][reg];
        }
      }
    }
    __syncthreads();
    int browbase = row0 + p * 64;
#pragma unroll
    for (int q = 0; q < 2; ++q) {
      int idx = t + 256 * q;          // 0..511
      int prow = idx >> 3;            // 0..63
      int cb = (idx & 7) * 16;        // 0..112 (float/col base within 128-col row)
      int grow = browbase + prow;
      if (grow < N) {
        const float* fp = &ldsf[prow * 132 + cb];
        unsigned ov[4];
#pragma unroll
        for (int q4 = 0; q4 < 4; ++q4) {
          unsigned v = 0;
          v = __builtin_amdgcn_cvt_pk_fp8_f32(fp[q4 * 4 + 0], fp[q4 * 4 + 1], v, false);
          v = __builtin_amdgcn_cvt_pk_fp8_f32(fp[q4 * 4 + 2], fp[q4 * 4 + 3], v, true);
          ov[q4] = v;
        }
        *(uint4*)(Cout8 + (size_t)grow * 256 + col0 + cb) =
            make_uint4(ov[0], ov[1], ov[2], ov[3]);
      }
    }
  }
}

// ---------------- fused SINGLE-PASS per-dst: exp + denom + aggregate + bias + tanh ----
// One wave per node, half-wave per alternating edge. The softmax denominator is
// accumulated inline with the gather (normalization was already deferred), so
// there is no separate e-value pass, no LDS stash, no 4-channel reduction.
__global__ __launch_bounds__(256) void attn_agg(const unsigned char* __restrict__ g8,
    const float* __restrict__ a_src, const float* __restrict__ a_dst,
    const int* __restrict__ row_start, const int* __restrict__ edge_src,
    const float* __restrict__ bias,
    unsigned short* __restrict__ hout_bf, float* __restrict__ nodemean, int N) {
  int lane = threadIdx.x & 63;
  int w = threadIdx.x >> 6;
  int n = blockIdx.x * 4 + w;
  if (n >= N) return;
  int beg = row_start[n], end = row_start[n + 1];

  int half = lane >> 5;
  int l = lane & 31;
  int h = l >> 3;          // head for this lane's 8 channels
  int c0 = l * 8;          // channel base (0..248)
  float adh = a_dst[(size_t)n * 4 + h];

  // single pass: per-edge e-value (computed in-lane; halves process different
  // edges in the same instruction slot), denominator + weighted sum together.
  floatx2 p0 = {0.f, 0.f}, p1 = {0.f, 0.f}, p2 = {0.f, 0.f}, p3 = {0.f, 0.f};
  float den = 0.f;
  int i = beg + half;
  for (; i + 6 < end; i += 8) {
    int s0 = edge_src[i];
    int s1 = edge_src[i + 2];
    int s2 = edge_src[i + 4];
    int s3 = edge_src[i + 6];
    float e0 = fast_exp(fminf(leaky(a_src[(size_t)s0 * 4 + h] + adh), 60.f));
    float e1 = fast_exp(fminf(leaky(a_src[(size_t)s1 * 4 + h] + adh), 60.f));
    float e2 = fast_exp(fminf(leaky(a_src[(size_t)s2 * 4 + h] + adh), 60.f));
    float e3 = fast_exp(fminf(leaky(a_src[(size_t)s3 * 4 + h] + adh), 60.f));
    den += (e0 + e1) + (e2 + e3);
    uint2 g0 = *(const uint2*)(g8 + (size_t)s0 * 256 + c0);
    uint2 g1 = *(const uint2*)(g8 + (size_t)s1 * 256 + c0);
    uint2 g2 = *(const uint2*)(g8 + (size_t)s2 * 256 + c0);
    uint2 g3 = *(const uint2*)(g8 + (size_t)s3 * 256 + c0);
    p0 += e0 * (floatx2)__builtin_amdgcn_cvt_pk_f32_fp8(g0.x, false)
        + e1 * (floatx2)__builtin_amdgcn_cvt_pk_f32_fp8(g1.x, false)
        + e2 * (floatx2)__builtin_amdgcn_cvt_pk_f32_fp8(g2.x, false)
        + e3 * (floatx2)__builtin_amdgcn_cvt_pk_f32_fp8(g3.x, false);
    p1 += e0 * (floatx2)__builtin_amdgcn_cvt_pk_f32_fp8(g0.x, true)
        + e1 * (floatx2)__builtin_amdgcn_cvt_pk_f32_fp8(g1.x, true)
        + e2 * (floatx2)__builtin_amdgcn_cvt_pk_f32_fp8(g2.x, true)
        + e3 * (floatx2)__builtin_amdgcn_cvt_pk_f32_fp8(g3.x, true);
    p2 += e0 * (floatx2)__builtin_amdgcn_cvt_pk_f32_fp8(g0.y, false)
        + e1 * (floatx2)__builtin_amdgcn_cvt_pk_f32_fp8(g1.y, false)
        + e2 * (floatx2)__builtin_amdgcn_cvt_pk_f32_fp8(g2.y, false)
        + e3 * (floatx2)__builtin_amdgcn_cvt_pk_f32_fp8(g3.y, false);
    p3 += e0 * (floatx2)__builtin_amdgcn_cvt_pk_f32_fp8(g0.y, true)
        + e1 * (floatx2)__builtin_amdgcn_cvt_pk_f32_fp8(g1.y, true)
        + e2 * (floatx2)__builtin_amdgcn_cvt_pk_f32_fp8(g2.y, true)
        + e3 * (floatx2)__builtin_amdgcn_cvt_pk_f32_fp8(g3.y, true);
  }
  for (; i < end; i += 2) {
    int s = edge_src[i];
    float e0 = fast_exp(fminf(leaky(a_src[(size_t)s * 4 + h] + adh), 60.f));
    den += e0;
    uint2 gv = *(const uint2*)(g8 + (size_t)s * 256 + c0);
    p0 += e0 * (floatx2)__builtin_amdgcn_cvt_pk_f32_fp8(gv.x, false);
    p1 += e0 * (floatx2)__builtin_amdgcn_cvt_pk_f32_fp8(gv.x, true);
    p2 += e0 * (floatx2)__builtin_amdgcn_cvt_pk_f32_fp8(gv.y, false);
    p3 += e0 * (floatx2)__builtin_amdgcn_cvt_pk_f32_fp8(gv.y, true);
  }
  float a0 = p0[0], a1 = p0[1], a2 = p1[0], a3 = p1[1];
  float a4 = p2[0], a5 = p2[1], a6 = p3[0], a7 = p3[1];
  // combine the two halves (disjoint edge subsets) for sums AND denominator
  a0 += __shfl_xor(a0, 32, 64); a1 += __shfl_xor(a1, 32, 64);
  a2 += __shfl_xor(a2, 32, 64); a3 += __shfl_xor(a3, 32, 64);
  a4 += __shfl_xor(a4, 32, 64); a5 += __shfl_xor(a5, 32, 64);
  a6 += __shfl_xor(a6, 32, 64); a7 += __shfl_xor(a7, 32, 64);
  den += __shfl_xor(den, 32, 64);
  float invh = __builtin_amdgcn_rcpf(den + SOFT_EPS);
  a0 *= invh; a1 *= invh; a2 *= invh; a3 *= invh;
  a4 *= invh; a5 *= invh; a6 *= invh; a7 *= invh;

  float4 b01 = *(const float4*)(bias + c0);
  float4 b23 = *(const float4*)(bias + c0 + 4);
  float o0 = fast_tanh(a0 + b01.x), o1 = fast_tanh(a1 + b01.y);
  float o2 = fast_tanh(a2 + b01.z), o3 = fast_tanh(a3 + b01.w);
  float o4 = fast_tanh(a4 + b23.x), o5 = fast_tanh(a5 + b23.y);
  float o6 = fast_tanh(a6 + b23.z), o7 = fast_tanh(a7 + b23.w);

  if (hout_bf) {
    if (half == 0) {
      unsigned q0 = (unsigned)f2bf(o0) | ((unsigned)f2bf(o1) << 16);
      unsigned q1 = (unsigned)f2bf(o2) | ((unsigned)f2bf(o3) << 16);
      unsigned q2 = (unsigned)f2bf(o4) | ((unsigned)f2bf(o5) << 16);
      unsigned q3 = (unsigned)f2bf(o6) | ((unsigned)f2bf(o7) << 16);
      *(uint4*)(hout_bf + (size_t)n * 256 + c0) = make_uint4(q0, q1, q2, q3);
    }
  } else {
    // head-mean: channel j over heads = lanes l, l+8, l+16, l+24
    o0 += __shfl_xor(o0, 8, 64);  o1 += __shfl_xor(o1, 8, 64);
    o2 += __shfl_xor(o2, 8, 64);  o3 += __shfl_xor(o3, 8, 64);
    o4 += __shfl_xor(o4, 8, 64);  o5 += __shfl_xor(o5, 8, 64);
    o6 += __shfl_xor(o6, 8, 64);  o7 += __shfl_xor(o7, 8, 64);
    o0 += __shfl_xor(o0, 16, 64); o1 += __shfl_xor(o1, 16, 64);
    o2 += __shfl_xor(o2, 16, 64); o3 += __shfl_xor(o3, 16, 64);
    o4 += __shfl_xor(o4, 16, 64); o5 += __shfl_xor(o5, 16, 64);
    o6 += __shfl_xor(o6, 16, 64); o7 += __shfl_xor(o7, 16, 64);
    if (half == 0 && l < 8) {
      float* np = nodemean + (size_t)n * 64 + l * 8;
      *(float4*)(np)     = make_float4(0.25f * o0, 0.25f * o1, 0.25f * o2, 0.25f * o3);
      *(float4*)(np + 4) = make_float4(0.25f * o4, 0.25f * o5, 0.25f * o6, 0.25f * o7);
    }
  }
}

// ---------------- readout ----------------
#define RNPB 256
__global__ __launch_bounds__(256) void readout_nodes(const float* __restrict__ nm,
    const int* __restrict__ batch, unsigned* __restrict__ gmax,
    float* __restrict__ gsum, int* __restrict__ cnt, int N) {
  int t = threadIdx.x;
  int c = t & 63;
  int q = t >> 6;
  int n0 = blockIdx.x * RNPB + q * (RNPB / 4);
  if (n0 >= N) return;
  int n1 = min(n0 + RNPB / 4, N);
  float vmax = -FLT_MAX, vsum = 0.f;
  int curb = batch[n0];
  int cl = 0;
  for (int n = n0; n < n1; ++n) {
    int b = batch[n];
    if (b != curb) {
      atomicMax(&gmax[curb * 64 + c], enc_f(vmax));
      atomicAdd(&gsum[curb * 64 + c], vsum);
      if (c == 0) atomicAdd(&cnt[curb], cl);
      vmax = -FLT_MAX; vsum = 0.f; cl = 0; curb = b;
    }
    float v = nm[(size_t)n * 64 + c];
    vmax = fmaxf(vmax, v); vsum += v; ++cl;
  }
  atomicMax(&gmax[curb * 64 + c], enc_f(vmax));
  atomicAdd(&gsum[curb * 64 + c], vsum);
  if (c == 0) atomicAdd(&cnt[curb], cl);
}

__global__ __launch_bounds__(256) void finalize(const unsigned* __restrict__ gmax,
    const float* __restrict__ gsum, const int* __restrict__ cnt,
    const float* __restrict__ Wout, const float* __restrict__ bout,
    float* __restrict__ out) {
  __shared__ float hid[64 * 192];
  int t = threadIdx.x;
  for (int i = t; i < 64 * 192; i += 256) {
    int b = i / 192, j = i % 192;
    float v;
    if (j < 64) v = dec_f(gmax[b * 64 + j]);
    else if (j < 128) v = gsum[b * 64 + j - 64] / fmaxf((float)cnt[b], 1.f);
    else v = gsum[b * 64 + j - 128];
    hid[i] = v;
    out[1024 + i] = v;
  }
  __syncthreads();
  for (int i = t; i < 64 * 16; i += 256) {
    int b = i >> 4, o = i & 15;
    float s = bout[o];
    for (int k = 0; k < 192; ++k) s += hid[b * 192 + k] * Wout[k * 16 + o];
    out[i] = s;
  }
}

extern "C" void kernel_launch(void* const* d_in, const int* in_sizes, int n_in,
                              void* d_out, int out_size, void* d_ws, size_t ws_size,
                              hipStream_t stream) {
  const float* x     = (const float*)d_in[0];
  const int*   ei    = (const int*)d_in[1];
  const int*   batch = (const int*)d_in[2];
  const float* W[3]  = {(const float*)d_in[3], (const float*)d_in[7], (const float*)d_in[11]};
  const float* as_[3] = {(const float*)d_in[4], (const float*)d_in[8], (const float*)d_in[12]};
  const float* ad_[3] = {(const float*)d_in[5], (const float*)d_in[9], (const float*)d_in[13]};
  const float* bb[3] = {(const float*)d_in[6], (const float*)d_in[10], (const float*)d_in[14]};
  const float* Wout  = (const float*)d_in[15];
  const float* bout  = (const float*)d_in[16];
  float* out = (float*)d_out;

  int N    = in_sizes[2];
  int Fin  = in_sizes[0] / N;
  int E    = in_sizes[1] / 2;
  int Etot = E + N;

  char* ws = (char*)d_ws;
  size_t off = 0;
  auto alloc = [&](size_t bytes) -> void* {
    void* p = ws + off;
    off += bytes;
    off = (off + 255) & ~(size_t)255;
    return p;
  };
  unsigned char* gbuf  = (unsigned char*)alloc((size_t)N * 256);       // gemm out (fp8)
  unsigned short* h0bf = (unsigned short*)alloc((size_t)N * Fin * 2);  // x (bf16)
  unsigned short* h1bf = (unsigned short*)alloc((size_t)N * 256 * 2);  // layer out (bf16)
  float* nodemean  = (float*)alloc((size_t)N * 64 * 4);                // layer-2 head-mean
  unsigned short* Wt[3];
  Wt[0] = (unsigned short*)alloc((size_t)256 * Fin * 2);
  Wt[1] = (unsigned short*)alloc((size_t)256 * 256 * 2);
  Wt[2] = (unsigned short*)alloc((size_t)256 * 256 * 2);
  float* a_src    = (float*)alloc((size_t)N * 4 * 4);
  float* a_dst    = (float*)alloc((size_t)N * 4 * 4);
  int* counts     = (int*)alloc((size_t)N * 4);
  int* row_start  = (int*)alloc((size_t)(N + 1) * 4);
  int* rank       = (int*)alloc((size_t)Etot * 4);
  int* edge_src   = (int*)alloc((size_t)Etot * 4);
  int* chunkSum   = (int*)alloc(64 * 4);
  int* chunkOff   = (int*)alloc(64 * 4);
  unsigned* gmax  = (unsigned*)alloc(64 * 64 * 4);
  float* gsum     = (float*)alloc(64 * 64 * 4);
  int* cnt        = (int*)alloc(64 * 4);

  // ---- CSR build: 1 atomic pass (count+rank), scan, atomic-free scatter ----
  hipMemsetAsync(counts, 0, (size_t)N * 4, stream);
  int nb = (N + 2047) / 2048;
  int egrid = (Etot + 1023) / 1024;   // 4 edges per thread
  count_deg<<<egrid, 256, 0, stream>>>(ei, E, N, counts, rank);
  chunk_sum<<<nb, 256, 0, stream>>>(counts, chunkSum, N);
  scan_chunks<<<1, 64, 0, stream>>>(chunkSum, chunkOff, nb, row_start, N, Etot,
                                    gmax, gsum, cnt);
  scan_emit<<<nb, 256, 0, stream>>>(counts, chunkOff, row_start, N);
  scatter_edges<<<egrid, 256, 0, stream>>>(ei, E, N, row_start, rank, edge_src);

  // ---- weight transpose-convert (one launch), x convert ----
  cvt_wt3<<<dim3(16, 16, 3), 256, 0, stream>>>(W[0], W[1], W[2], Wt[0], Wt[1], Wt[2], Fin);
  cvt_bf16<<<((N * Fin / 4) + 255) / 256, 256, 0, stream>>>(x, h0bf, N * Fin / 4);

  // ---- 3 GAT layers ----
  const unsigned short* Ain = h0bf;
  int K = Fin;
  for (int l = 0; l < 3; ++l) {
    dim3 gg(2, (N + BM - 1) / BM);
    gemm_core<<<gg, 256, 0, stream>>>(Ain, Wt[l], gbuf, a_src, a_dst,
                                      as_[l], ad_[l], N, K);
    attn_agg<<<(N + 3) / 4, 256, 0, stream>>>(gbuf, a_src, a_dst, row_start, edge_src,
                                              bb[l],
                                              (l < 2) ? h1bf : (unsigned short*)nullptr,
                                              (l == 2) ? nodemean : (float*)nullptr, N);
    Ain = h1bf;
    K = 256;
  }

  // ---- readout ----
  readout_nodes<<<(N + RNPB - 1) / RNPB, 256, 0, stream>>>(nodemean, batch, gmax, gsum, cnt, N);
  finalize<<<1, 256, 0, stream>>>(gmax, gsum, cnt, Wout, bout, out);
}